// Round 10
// baseline (28.020 us; speedup 1.0000x reference)
//
#include <hip/hip_runtime.h>

// AttnCutLoss: loss = -(1/B) * sum_b [ (sum_s log(output[b,s])) / (sum_s exp(r_bs/TAU)) ]
// r_bs = 2*tp_bs / (k + total_b)   (F1, algebraically simplified; exact for the
// reference's tp=0 / total=0 where() branches).  B = S = 4096, TAU = 0.95, fp32.
//
// R9 (nt loads, lane-contiguous, hierarchical scan) + 2 rows per block in a
// plain sequential loop: amortizes block setup/drain, halves block churn.
// No launch_bounds cap beyond BDIM (R4's waves/EU=6 cap hurt).

#define BDIM 256
#define NCH 4               // float4 chunks per thread; BDIM*NCH*4 == SROW
#define ROWSPB 2
#define SROW 4096
#define NROWS 4096

typedef float vf4 __attribute__((ext_vector_type(4)));

__global__ __launch_bounds__(BDIM) void attncut_row_kernel(
    const float* __restrict__ output,   // [B,S,1]
    const float* __restrict__ labels,   // [B,S]
    float* __restrict__ row_out)        // [B] : L_b / norm_b
{
    const int tid  = threadIdx.x;       // 0..255
    const int lane = tid & 63;
    const int wave = tid >> 6;          // 0..3
    const int r0   = blockIdx.x * ROWSPB;

    __shared__ float wtot[NCH * 4], wpre[NCH * 4];
    __shared__ float s_total;
    __shared__ float sq[4], sl[4];

    for (int r = 0; r < ROWSPB; ++r) {
        const int b = r0 + r;
        const vf4* lab4 = reinterpret_cast<const vf4*>(labels) + (size_t)b * (SROW / 4) + tid;
        const vf4* out4 = reinterpret_cast<const vf4*>(output) + (size_t)b * (SROW / 4) + tid;

        // Issue all loads up front; nt = no L2 allocate / evict-first.
        vf4 Lv[NCH], Ov[NCH];
        #pragma unroll
        for (int k = 0; k < NCH; ++k) Lv[k] = __builtin_nontemporal_load(&lab4[k * BDIM]);
        #pragma unroll
        for (int k = 0; k < NCH; ++k) Ov[k] = __builtin_nontemporal_load(&out4[k * BDIM]);

        // Per-chunk local inclusive prefixes (labels are exactly 0.0/1.0 -> exact).
        float p[NCH][4], s[NCH];
        #pragma unroll
        for (int k = 0; k < NCH; ++k) {
            p[k][0] = Lv[k].x;
            p[k][1] = p[k][0] + Lv[k].y;
            p[k][2] = p[k][1] + Lv[k].z;
            p[k][3] = p[k][2] + Lv[k].w;
            s[k]    = p[k][3];
        }

        // 4 independent wave-level inclusive scans.
        float sc[NCH];
        #pragma unroll
        for (int k = 0; k < NCH; ++k) sc[k] = s[k];
        #pragma unroll
        for (int d = 1; d < 64; d <<= 1) {
            #pragma unroll
            for (int k = 0; k < NCH; ++k) {
                float n = __shfl_up(sc[k], d, 64);
                if (lane >= d) sc[k] += n;
            }
        }

        // lsum: O-loads have had the whole scan to arrive.
        float lsum = 0.f;
        #pragma unroll
        for (int k = 0; k < NCH; ++k)
            lsum += __logf(Ov[k].x) + __logf(Ov[k].y) + __logf(Ov[k].z) + __logf(Ov[k].w);

        // Cross-wave / cross-chunk exclusive prefixes via 16-value LDS scan.
        // Row position = (k*BDIM + tid)*4 + j -> scan order k-major: idx = k*4 + wave.
        if (r > 0) __syncthreads();     // protect smem reuse across iterations
        if (lane == 63) {
            #pragma unroll
            for (int k = 0; k < NCH; ++k) wtot[k * 4 + wave] = sc[k];
        }
        __syncthreads();
        if (tid == 0) {
            float a = 0.f;
            #pragma unroll
            for (int i = 0; i < NCH * 4; ++i) { wpre[i] = a; a += wtot[i]; }
            s_total = a;
        }
        __syncthreads();
        const float total = s_total;

        // qsum = sum exp(2*tp / (TAU*(rank+total))), fast rcp for the divide.
        const float c = 2.0f / 0.95f;
        float qsum = 0.f;
        #pragma unroll
        for (int k = 0; k < NCH; ++k) {
            const float excl = wpre[k * 4 + wave] + (sc[k] - s[k]);
            const float rbase = (float)(4 * (k * BDIM + tid) + 1) + total;
            #pragma unroll
            for (int j = 0; j < 4; ++j) {
                float tp = excl + p[k][j];
                qsum += __expf(c * tp * __builtin_amdgcn_rcpf(rbase + (float)j));
            }
        }

        // Block reduction of (qsum, lsum).
        #pragma unroll
        for (int d = 32; d > 0; d >>= 1) {
            qsum += __shfl_down(qsum, d, 64);
            lsum += __shfl_down(lsum, d, 64);
        }
        if (lane == 0) { sq[wave] = qsum; sl[wave] = lsum; }
        __syncthreads();
        if (tid == 0) {
            float Q = 0.f, L = 0.f;
            #pragma unroll
            for (int w = 0; w < 4; ++w) { Q += sq[w]; L += sl[w]; }
            row_out[b] = L / Q;
        }
    }
}

__global__ __launch_bounds__(256) void attncut_final_kernel(
    const float* __restrict__ row_out, float* __restrict__ d_out)
{
    const int tid = threadIdx.x;            // 0..255
    const int lane = tid & 63, wave = tid >> 6;
    const float4* r4 = reinterpret_cast<const float4*>(row_out);
    float s = 0.f;
    #pragma unroll
    for (int k = 0; k < 4; ++k) {
        float4 v = r4[tid + k * 256];
        s += v.x + v.y + v.z + v.w;
    }
    #pragma unroll
    for (int d = 32; d > 0; d >>= 1) s += __shfl_down(s, d, 64);
    __shared__ float sm[4];
    if (lane == 0) sm[wave] = s;
    __syncthreads();
    if (tid == 0) {
        float t = sm[0] + sm[1] + sm[2] + sm[3];
        d_out[0] = -t / (float)NROWS;
    }
}

extern "C" void kernel_launch(void* const* d_in, const int* in_sizes, int n_in,
                              void* d_out, int out_size, void* d_ws, size_t ws_size,
                              hipStream_t stream) {
    const float* output = (const float*)d_in[0];   // [B,S,1] fp32
    const float* labels = (const float*)d_in[1];   // [B,S]   fp32
    float* out  = (float*)d_out;
    float* rows = (float*)d_ws;                    // NROWS floats of scratch

    attncut_row_kernel<<<NROWS / ROWSPB, BDIM, 0, stream>>>(output, labels, rows);
    attncut_final_kernel<<<1, 256, 0, stream>>>(rows, out);
}

// Round 11
// 26.321 us; speedup vs baseline: 1.0646x; 1.0646x over previous
//
#include <hip/hip_runtime.h>

// AttnCutLoss: loss = -(1/B) * sum_b [ (sum_s log(output[b,s])) / (sum_s exp(r_bs/TAU)) ]
// r_bs = 2*tp_bs / (k + total_b)   (F1, algebraically simplified; exact for the
// reference's tp=0 / total=0 where() branches).  B = S = 4096, TAU = 0.95, fp32.
//
// Best config (R9): 1 row per 256-thread block, lane-contiguous nontemporal
// loads (nt = no L2 allocate; the two 64 MB single-use streams would thrash the
// 32 MB aggregate L2), hierarchical label scan (4 wave scans + 16-value LDS
// scan), fast-rcp divide, two-kernel tree reduction (single-address atomics
// and device fences measured 2.4x-5x slower).

#define BDIM 256
#define NCH 4               // float4 chunks per thread; BDIM*NCH*4 == SROW
#define SROW 4096
#define NROWS 4096

typedef float vf4 __attribute__((ext_vector_type(4)));

__global__ __launch_bounds__(BDIM) void attncut_row_kernel(
    const float* __restrict__ output,   // [B,S,1]
    const float* __restrict__ labels,   // [B,S]
    float* __restrict__ row_out)        // [B] : L_b / norm_b
{
    const int b    = blockIdx.x;
    const int tid  = threadIdx.x;       // 0..255
    const int lane = tid & 63;
    const int wave = tid >> 6;          // 0..3

    const vf4* lab4 = reinterpret_cast<const vf4*>(labels) + (size_t)b * (SROW / 4) + tid;
    const vf4* out4 = reinterpret_cast<const vf4*>(output) + (size_t)b * (SROW / 4) + tid;

    // Issue all loads up front; nt flag = no L2 allocate / evict-first.
    vf4 Lv[NCH], Ov[NCH];
    #pragma unroll
    for (int k = 0; k < NCH; ++k) Lv[k] = __builtin_nontemporal_load(&lab4[k * BDIM]);
    #pragma unroll
    for (int k = 0; k < NCH; ++k) Ov[k] = __builtin_nontemporal_load(&out4[k * BDIM]);

    // Per-chunk local inclusive prefixes (labels are exactly 0.0/1.0 -> exact).
    float p[NCH][4], s[NCH];
    #pragma unroll
    for (int k = 0; k < NCH; ++k) {
        p[k][0] = Lv[k].x;
        p[k][1] = p[k][0] + Lv[k].y;
        p[k][2] = p[k][1] + Lv[k].z;
        p[k][3] = p[k][2] + Lv[k].w;
        s[k]    = p[k][3];
    }

    // 4 independent wave-level inclusive scans (good ILP, pure VALU).
    float sc[NCH];
    #pragma unroll
    for (int k = 0; k < NCH; ++k) sc[k] = s[k];
    #pragma unroll
    for (int d = 1; d < 64; d <<= 1) {
        #pragma unroll
        for (int k = 0; k < NCH; ++k) {
            float n = __shfl_up(sc[k], d, 64);
            if (lane >= d) sc[k] += n;
        }
    }

    // lsum here: O-loads have had the whole scan to arrive.
    float lsum = 0.f;
    #pragma unroll
    for (int k = 0; k < NCH; ++k)
        lsum += __logf(Ov[k].x) + __logf(Ov[k].y) + __logf(Ov[k].z) + __logf(Ov[k].w);

    // Cross-wave / cross-chunk exclusive prefixes via 16-value LDS scan.
    // Row position = (k*BDIM + tid)*4 + j  ->  scan order k-major: index = k*4 + wave.
    __shared__ float wtot[NCH * 4], wpre[NCH * 4];
    __shared__ float s_total;
    if (lane == 63) {
        #pragma unroll
        for (int k = 0; k < NCH; ++k) wtot[k * 4 + wave] = sc[k];
    }
    __syncthreads();
    if (tid == 0) {
        float a = 0.f;
        #pragma unroll
        for (int i = 0; i < NCH * 4; ++i) { wpre[i] = a; a += wtot[i]; }
        s_total = a;
    }
    __syncthreads();
    const float total = s_total;

    // qsum = sum exp(2*tp / (TAU*(rank+total))), fast rcp for the divide.
    const float c = 2.0f / 0.95f;
    float qsum = 0.f;
    #pragma unroll
    for (int k = 0; k < NCH; ++k) {
        const float excl = wpre[k * 4 + wave] + (sc[k] - s[k]);
        const float rbase = (float)(4 * (k * BDIM + tid) + 1) + total;
        #pragma unroll
        for (int j = 0; j < 4; ++j) {
            float tp = excl + p[k][j];
            qsum += __expf(c * tp * __builtin_amdgcn_rcpf(rbase + (float)j));
        }
    }

    // Block reduction of (qsum, lsum).
    #pragma unroll
    for (int d = 32; d > 0; d >>= 1) {
        qsum += __shfl_down(qsum, d, 64);
        lsum += __shfl_down(lsum, d, 64);
    }
    __shared__ float sq[4], sl[4];
    if (lane == 0) { sq[wave] = qsum; sl[wave] = lsum; }
    __syncthreads();
    if (tid == 0) {
        float Q = 0.f, L = 0.f;
        #pragma unroll
        for (int w = 0; w < 4; ++w) { Q += sq[w]; L += sl[w]; }
        row_out[b] = L / Q;
    }
}

__global__ __launch_bounds__(256) void attncut_final_kernel(
    const float* __restrict__ row_out, float* __restrict__ d_out)
{
    const int tid = threadIdx.x;            // 0..255
    const int lane = tid & 63, wave = tid >> 6;
    const float4* r4 = reinterpret_cast<const float4*>(row_out);
    float s = 0.f;
    #pragma unroll
    for (int k = 0; k < 4; ++k) {
        float4 v = r4[tid + k * 256];
        s += v.x + v.y + v.z + v.w;
    }
    #pragma unroll
    for (int d = 32; d > 0; d >>= 1) s += __shfl_down(s, d, 64);
    __shared__ float sm[4];
    if (lane == 0) sm[wave] = s;
    __syncthreads();
    if (tid == 0) {
        float t = sm[0] + sm[1] + sm[2] + sm[3];
        d_out[0] = -t / (float)NROWS;
    }
}

extern "C" void kernel_launch(void* const* d_in, const int* in_sizes, int n_in,
                              void* d_out, int out_size, void* d_ws, size_t ws_size,
                              hipStream_t stream) {
    const float* output = (const float*)d_in[0];   // [B,S,1] fp32
    const float* labels = (const float*)d_in[1];   // [B,S]   fp32
    float* out  = (float*)d_out;
    float* rows = (float*)d_ws;                    // NROWS floats of scratch

    attncut_row_kernel<<<NROWS, BDIM, 0, stream>>>(output, labels, rows);
    attncut_final_kernel<<<1, 256, 0, stream>>>(rows, out);
}